// Round 1
// baseline (164.519 us; speedup 1.0000x reference)
//
#include <hip/hip_runtime.h>
#include <hip/hip_bf16.h>
#include <hip/hip_fp16.h>

// Problem constants (match reference)
#define CUTOFF_C    12.0f
#define CUTOFF_SR_C 2.0f
#define CUTOFF_SQ_C 144.0f
#define KEHALF_C    7.199822675975274f

#define BLK1   1024

// Old-path duo config: 2 blocks/CU. 17408*4 + 1025*8 = 77832 B <= 80 KB.
#define CH_DUO   17408
#define LUT_DUO  1024
// Old-path solo config: 1 block/CU.
#define CH_SOLO  33792
#define LUT_SOLO 2048

// New-path record scatter: no LUT in LDS -> CH*4 = 80000 B <= 80 KB, nch=5.
#define CH_REC   20000

__device__ __forceinline__ float edge_energy(float d, float qi, float qj,
                                             float di, float dj) {
    float inv_d   = __frcp_rn(d);
    float dsh     = __fsqrt_rn(fmaf(d, d, 1.0f));
    float inv_dsh = __frcp_rn(dsh);
    float x  = d * (1.0f / CUTOFF_SR_C);
    float x3 = x * x * x;
    float sw = fmaf(x3, fmaf(x, fmaf(x, -6.0f, 15.0f), -10.0f), 1.0f);
    float sw_off = (d < CUTOFF_SR_C) ? sw : 0.0f;
    float Eoq = inv_d   + fmaf(d,   (1.0f / CUTOFF_SQ_C), -(2.0f / CUTOFF_C));
    float Esq = inv_dsh + fmaf(dsh, (1.0f / CUTOFF_SQ_C), -(2.0f / CUTOFF_C));
    float Eq  = (KEHALF_C * qi * qj) * fmaf(sw_off, Esq - Eoq, Eoq);
    float Eod = inv_d * inv_d * inv_d;
    float Esd = inv_dsh * inv_dsh * inv_dsh;
    float Ed  = (KEHALF_C * di * dj) * fmaf(sw_off, Esd - Eod, Eod);
    return Eq + Ed;
}

// Exact radial factors (KEHALF folded): v = qj*F, w = dj*G.  (old path / LUT init)
__device__ __forceinline__ float2 fg_exact(float d) {
    float inv_d   = 1.0f / d;
    float dsh     = sqrtf(fmaf(d, d, 1.0f));
    float inv_dsh = 1.0f / dsh;
    float x  = d * (1.0f / CUTOFF_SR_C);
    float x3 = x * x * x;
    float sw = fmaf(x3, fmaf(x, fmaf(x, -6.0f, 15.0f), -10.0f), 1.0f);
    float sw_off = (d < CUTOFF_SR_C) ? sw : 0.0f;
    float Foq = inv_d   + fmaf(d,   (1.0f / CUTOFF_SQ_C), -(2.0f / CUTOFF_C));
    float Fsq = inv_dsh + fmaf(dsh, (1.0f / CUTOFF_SQ_C), -(2.0f / CUTOFF_C));
    float F   = fmaf(sw_off, Fsq - Foq, Foq);
    float God = inv_d * inv_d * inv_d;
    float Gsd = inv_dsh * inv_dsh * inv_dsh;
    float G   = fmaf(sw_off, Gsd - God, God);
    return make_float2(KEHALF_C * F, KEHALF_C * G);
}

__device__ __forceinline__ __half2 vw_make_exact(float d, __half2 hqdj) {
    float2 qdj = __half22float2(hqdj);
    float2 fg  = fg_exact(d);
    return __floats2half2_rn(qdj.x * fg.x, qdj.y * fg.y);
}

__device__ __forceinline__ unsigned h2bits(__half2 h) {
    union { __half2 h; unsigned u; } c; c.h = h; return c.u;
}
__device__ __forceinline__ __half2 bits2h(unsigned u) {
    union { unsigned u; __half2 h; } c; c.u = u; return c.h;
}
// half2 atomic add: HW atomicAdd(__half2*) (ds_pk_add_f16) if available.
template <typename T>
__device__ __forceinline__ auto atom_add_h2(T* p, T v, int)
    -> decltype(atomicAdd(p, v), void()) {
    atomicAdd(p, v);
}
template <typename T>
__device__ __forceinline__ void atom_add_h2(T* p, T v, long) {
    unsigned* u = (unsigned*)p;
    unsigned old = *u, assumed;
    do {
        assumed = old;
        __half2 sum = __hadd2(bits2h(assumed), v);
        old = atomicCAS(u, assumed, h2bits(sum));
    } while (old != assumed);
}

// Fast-exact per-edge radial factors via HW rcp/rsq (errors << fp16 rounding).
// Returns half2{qj*F, dipj*G} bit-pattern. hq must be zeroed for invalid edges.
__device__ __forceinline__ unsigned vw_bits(float d, __half2 hq) {
    float inv_d   = __builtin_amdgcn_rcpf(d);
    float dsh2    = fmaf(d, d, 1.0f);
    float inv_dsh = __builtin_amdgcn_rsqf(dsh2);   // 1/sqrt(d^2+1)
    float dsh     = dsh2 * inv_dsh;                // sqrt(d^2+1)
    float x  = d * (1.0f / CUTOFF_SR_C);
    float x3 = x * x * x;
    float sw = fmaf(x3, fmaf(x, fmaf(x, -6.0f, 15.0f), -10.0f), 1.0f);
    float sw_off = (d < CUTOFF_SR_C) ? sw : 0.0f;
    float Foq = inv_d   + fmaf(d,   (1.0f / CUTOFF_SQ_C), -(2.0f / CUTOFF_C));
    float Fsq = inv_dsh + fmaf(dsh, (1.0f / CUTOFF_SQ_C), -(2.0f / CUTOFF_C));
    float F   = fmaf(sw_off, Fsq - Foq, Foq);
    float God = inv_d * inv_d * inv_d;
    float Gsd = inv_dsh * inv_dsh * inv_dsh;
    float G   = fmaf(sw_off, Gsd - God, God);
    float2 q2 = __half22float2(hq);
    __half2 vw = __floats2half2_rn((KEHALF_C * q2.x) * F, (KEHALF_C * q2.y) * G);
    return h2bits(vw);
}

// Pack {q, dip} -> half2 (4 B / atom), j-side gather table.
__global__ __launch_bounds__(256) void pc_pack_qd_h(
    const float* __restrict__ q,
    const float* __restrict__ dip,
    __half2*     __restrict__ qd,
    int n_atoms)
{
    int a = blockIdx.x * 256 + threadIdx.x;
    if (a < n_atoms) qd[a] = __floats2half2_rn(q[a], dip[a]);
}

// ---------------- NEW PASS A: per-edge precompute ----------------
// One full-lane-efficiency sweep over the edge tri-stream. Emits 8 B records
// {i (or ~0u sentinel if d>cutoff), half2{qj*F, dipj*G}}. Record ORDER is
// irrelevant to the consumer, so the two 16 B stores per lane go to disjoint
// dense regions (rec4[g] and rec4[n4+g]) -> both stores fully coalesced.
__global__ __launch_bounds__(256) void pc_edge_pre(
    const float*   __restrict__ dist,
    const int*     __restrict__ idx_i,
    const int*     __restrict__ idx_j,
    const __half2* __restrict__ qd,
    uint4*         __restrict__ rec4,    // 2 records per uint4
    int n_edges, int n4)
{
    const __half2 hzero = __floats2half2_rn(0.0f, 0.0f);
    const int t0     = blockIdx.x * 256 + (int)threadIdx.x;
    const int stride = gridDim.x * 256;
    const int4*   i4p = (const int4*)idx_i;
    const int4*   j4p = (const int4*)idx_j;
    const float4* d4p = (const float4*)dist;

    for (int g = t0; g < n4; g += stride) {
        int4   i4 = i4p[g];
        int4   j4 = j4p[g];
        float4 d4 = d4p[g];

        int   ii[4] = { i4.x, i4.y, i4.z, i4.w };
        int   jj[4] = { j4.x, j4.y, j4.z, j4.w };
        float dd[4] = { d4.x, d4.y, d4.z, d4.w };
        bool     vl[4];
        __half2  qh[4];
        unsigned ir[4], vwr[4];

        #pragma unroll
        for (int k = 0; k < 4; ++k) vl[k] = dd[k] <= CUTOFF_C;
        #pragma unroll
        for (int k = 0; k < 4; ++k) qh[k] = vl[k] ? qd[jj[k]] : hzero;
        #pragma unroll
        for (int k = 0; k < 4; ++k) {
            ir[k]  = vl[k] ? (unsigned)ii[k] : 0xFFFFFFFFu;
            vwr[k] = vw_bits(dd[k], qh[k]);
        }
        rec4[g]      = make_uint4(ir[0], vwr[0], ir[1], vwr[1]);
        rec4[n4 + g] = make_uint4(ir[2], vwr[2], ir[3], vwr[3]);
    }

    // scalar tail (n_edges % 4) -> records [4*n4, n_edges)
    uint2* rec2 = (uint2*)rec4;
    for (int e = (n4 << 2) + t0; e < n_edges; e += stride) {
        float d = dist[e];
        bool  v = d <= CUTOFF_C;
        __half2 hq = v ? qd[idx_j[e]] : hzero;
        rec2[e] = make_uint2(v ? (unsigned)idx_i[e] : 0xFFFFFFFFu, vw_bits(d, hq));
    }
}

// ---------------- NEW PASS B: record scatter ----------------
// Chunked-LDS scatter over precomputed records: per record just
// {lc = i - base; if (lc < CH) ds_pk_add_f16}. No gathers, no LUT, no fg math.
// Block b: s = b % S (record slice), c = b / S (atom chunk). S % 8 == 0 keeps
// same-slice blocks on one XCD so the 5 chunk re-reads hit L2.
template <int CH, int BLK>
__global__ __launch_bounds__(BLK) void pc_scatter_rec(
    const uint4* __restrict__ rec4,
    __half2*     __restrict__ partial,   // [S][n_atoms] half2 {sumv,sumw}
    int n_edges, int nv2, int S, int gps, int n_atoms)
{
    extern __shared__ char smem[];
    __half2* acc2 = (__half2*)smem;                                  // CH

    const int s = blockIdx.x % S;
    const int c = blockIdx.x / S;
    const unsigned base = (unsigned)(c * CH);
    const int lim = min(CH, n_atoms - (int)base);

    const __half2 hzero = __floats2half2_rn(0.0f, 0.0f);
    for (int i = threadIdx.x; i < CH; i += BLK) acc2[i] = hzero;
    __syncthreads();

    const int g0 = s * gps;
    const int g1 = min(g0 + gps, nv2);
    for (int g = g0 + (int)threadIdx.x; g < g1; g += BLK) {
        uint4 r = rec4[g];
        unsigned lc0 = r.x - base;
        unsigned lc1 = r.z - base;
        if (lc0 < (unsigned)CH) atom_add_h2(&acc2[lc0], bits2h(r.y), 0);
        if (lc1 < (unsigned)CH) atom_add_h2(&acc2[lc1], bits2h(r.w), 0);
    }

    if (s == S - 1 && (n_edges & 1)) {      // odd tail record
        if (threadIdx.x == 0) {
            const uint2* rec2 = (const uint2*)rec4;
            uint2 r = rec2[n_edges - 1];
            unsigned lc = r.x - base;
            if (lc < (unsigned)CH) atom_add_h2(&acc2[lc], bits2h(r.y), 0);
        }
    }

    __syncthreads();
    __half2* row = partial + (size_t)s * n_atoms + (int)base;
    for (int i = threadIdx.x; i < lim; i += BLK) row[i] = acc2[i];
}

// ---------------- OLD PATH (fallback): fused compute+scatter with LDS LUT ----
template <int CH, int LUTN, int BLK>
__global__ __launch_bounds__(BLK) void pc_scatter_lut(
    const float*   __restrict__ dist,
    const int*     __restrict__ idx_i,
    const int*     __restrict__ idx_j,
    const __half2* __restrict__ qd,
    __half2*       __restrict__ partial,   // [S][n_atoms] half2 {sumv,sumw}
    int n_edges, int n4, int S, int gps, int n_atoms, int nch)
{
    extern __shared__ char smem[];
    __half2* acc2 = (__half2*)smem;                                  // CH
    float2*  lut  = (float2*)(smem + (size_t)CH * sizeof(__half2));  // LUTN+1

    const int s    = blockIdx.x % S;
    const int c    = blockIdx.x / S;
    const int base = c * CH;
    const int lim  = min(CH, n_atoms - base);

    const __half2 hzero = __floats2half2_rn(0.0f, 0.0f);
    for (int i = threadIdx.x; i < CH; i += BLK) acc2[i] = hzero;

    const float hstep = CUTOFF_C / (float)LUTN;
    for (int k = threadIdx.x; k <= LUTN; k += BLK) {
        float d = fmaxf((float)k * hstep, 0.25f * hstep);
        lut[k] = fg_exact(d);
    }
    __syncthreads();

    const int g0 = s * gps;
    const int g1 = min(g0 + gps, n4);
    const int4*   idxi4 = (const int4*)idx_i;
    const int4*   idxj4 = (const int4*)idx_j;
    const float4* dist4 = (const float4*)dist;
    const float   dscale = (float)LUTN / CUTOFF_C;

    for (int g = g0 + (int)threadIdx.x; g < g1; g += BLK) {
        int4   i4 = idxi4[g];
        int4   j4 = idxj4[g];
        float4 d4 = dist4[g];

        int      ii[4] = { i4.x, i4.y, i4.z, i4.w };
        int      jj[4] = { j4.x, j4.y, j4.z, j4.w };
        float    dd[4] = { d4.x, d4.y, d4.z, d4.w };
        unsigned lc[4];
        bool     vl[4];
        __half2  qh[4];

        #pragma unroll
        for (int k = 0; k < 4; ++k) {
            lc[k] = (unsigned)(ii[k] - base);
            vl[k] = (lc[k] < (unsigned)CH) && (dd[k] <= CUTOFF_C);
        }
        #pragma unroll
        for (int k = 0; k < 4; ++k)
            qh[k] = vl[k] ? qd[jj[k]] : hzero;

        #pragma unroll
        for (int k = 0; k < 4; ++k) {
            if (vl[k]) {
                float t  = dd[k] * dscale;
                int   kk = min((int)t, LUTN - 1);
                float fr = t - (float)kk;
                float2 l0 = lut[kk];
                float2 l1 = lut[kk + 1];
                float F = fmaf(fr, l1.x - l0.x, l0.x);
                float G = fmaf(fr, l1.y - l0.y, l0.y);
                float2 qdj = __half22float2(qh[k]);
                __half2 vw = __floats2half2_rn(qdj.x * F, qdj.y * G);
                atom_add_h2(&acc2[lc[k]], vw, 0);
            }
        }
    }

    if (s == S - 1) {  // scalar tail (n_edges % 4)
        for (int e = (n4 << 2) + (int)threadIdx.x; e < n_edges; e += BLK) {
            int i = idx_i[e];
            float d = dist[e];
            unsigned local = (unsigned)(i - base);
            if (local < (unsigned)CH && d <= CUTOFF_C) {
                __half2 vw = vw_make_exact(d, qd[idx_j[e]]);
                atom_add_h2(&acc2[local], vw, 0);
            }
        }
    }

    __syncthreads();
    __half2* row = partial + (size_t)s * n_atoms + base;
    for (int i = threadIdx.x; i < lim; i += BLK) row[i] = acc2[i];
}

// out[a] = q[a]*sum_s(v) + dip[a]*sum_s(w) — exact fp32 recombination.
__global__ __launch_bounds__(256) void pc_reduce_vw(
    const __half2* __restrict__ partial,   // [S][n_atoms]
    const float*   __restrict__ q,
    const float*   __restrict__ dip,
    float*         __restrict__ out,
    int n_atoms, int S)
{
    __shared__ float2 sh[256];
    int a0   = blockIdx.x * 64;
    int lane = threadIdx.x & 63;
    int w    = threadIdx.x >> 6;
    int a    = a0 + lane;

    float sv = 0.0f, sw = 0.0f;
    if (a < n_atoms) {
        int per = S >> 2;                  // S % 4 == 0
        const __half2* p = partial + a;
        int s = w * per, send = s + per;
        for (; s < send; ++s) {
            float2 t = __half22float2(p[(size_t)s * n_atoms]);
            sv += t.x; sw += t.y;
        }
    }
    sh[threadIdx.x] = make_float2(sv, sw);
    __syncthreads();
    if (w == 0 && a < n_atoms) {
        float2 t0 = sh[lane],       t1 = sh[64 + lane];
        float2 t2 = sh[128 + lane], t3 = sh[192 + lane];
        float fv = (t0.x + t1.x) + (t2.x + t3.x);
        float fw = (t0.y + t1.y) + (t2.y + t3.y);
        out[a] = fmaf(q[a], fv, dip[a] * fw);
    }
}

// Full-precision global-atomic fallback (probe failure / tiny ws).
__global__ __launch_bounds__(256) void pc_dipole_edges_atomic(
    const float* __restrict__ q,
    const float* __restrict__ dip,
    const float* __restrict__ dist,
    const int*   __restrict__ idx_i,
    const int*   __restrict__ idx_j,
    float*       __restrict__ out,
    int n_edges)
{
    int t = blockIdx.x * blockDim.x + threadIdx.x;
    const int stride = gridDim.x * blockDim.x;
    for (int e = t; e < n_edges; e += stride) {
        float d = dist[e];
        if (d > CUTOFF_C) continue;
        int i = idx_i[e], j = idx_j[e];
        atomicAdd(&out[i], edge_energy(d, q[i], q[j], dip[i], dip[j]));
    }
}

static int probe_blocks(const void* f, int blk, size_t lds) {
    hipError_t e1 = hipFuncSetAttribute(
        f, hipFuncAttributeMaxDynamicSharedMemorySize, (int)lds);
    int nb = 0;
    hipError_t e2 = hipOccupancyMaxActiveBlocksPerMultiprocessor(&nb, f, blk, lds);
    if (e1 != hipSuccess || e2 != hipSuccess) return 0;
    return nb;
}

extern "C" void kernel_launch(void* const* d_in, const int* in_sizes, int n_in,
                              void* d_out, int out_size, void* d_ws, size_t ws_size,
                              hipStream_t stream) {
    const float* q     = (const float*)d_in[0];
    const float* dip   = (const float*)d_in[1];
    const float* dist  = (const float*)d_in[2];
    const int*   idx_i = (const int*)d_in[3];
    const int*   idx_j = (const int*)d_in[4];
    float*       out   = (float*)d_out;

    int n_edges = in_sizes[2];
    int n_atoms = out_size;
    int n4      = n_edges >> 2;
    int nv2     = n_edges >> 1;

    // ---------- NEW path: edge-precompute + record scatter ----------
    size_t qd_b   = ((size_t)n_atoms * sizeof(__half2) + 255) & ~(size_t)255;
    size_t rec_b  = (((size_t)n_edges * 8) + 255) & ~(size_t)255;
    size_t lds_rec = (size_t)CH_REC * sizeof(__half2);               // 80000 B

    int nb_rec = probe_blocks((const void*)&pc_scatter_rec<CH_REC, BLK1>,
                              BLK1, lds_rec);

    int S_new = 0, nch_new = 0;
    if (nb_rec >= 2 && n_atoms > 0 && ws_size > qd_b + rec_b) {
        nch_new = (n_atoms + CH_REC - 1) / CH_REC;                   // 5 for 100K
        int cap = 512;                                               // 2/CU * 256
        S_new = (cap / nch_new) & ~7;                                // 96
        size_t avail = ws_size - qd_b - rec_b;
        int S_fit = (int)(avail / ((size_t)n_atoms * sizeof(__half2))) & ~7;
        if (S_fit < S_new) S_new = S_fit;
    }

    if (S_new >= 8) {
        __half2* qd      = (__half2*)d_ws;
        uint4*   rec4    = (uint4*)((char*)d_ws + qd_b);
        __half2* partial = (__half2*)((char*)d_ws + qd_b + rec_b);
        int      gps     = (nv2 + S_new - 1) / S_new;

        pc_pack_qd_h<<<(n_atoms + 255) / 256, 256, 0, stream>>>(q, dip, qd,
                                                                n_atoms);
        int gridA = (n_edges + 1023) / 1024;
        if (gridA > 2048) gridA = 2048;
        if (gridA < 1)    gridA = 1;
        pc_edge_pre<<<gridA, 256, 0, stream>>>(dist, idx_i, idx_j, qd, rec4,
                                               n_edges, n4);
        pc_scatter_rec<CH_REC, BLK1>
            <<<S_new * nch_new, BLK1, lds_rec, stream>>>(
                rec4, partial, n_edges, nv2, S_new, gps, n_atoms);
        pc_reduce_vw<<<(n_atoms + 63) / 64, 256, 0, stream>>>(
            partial, q, dip, out, n_atoms, S_new);
        return;
    }

    // ---------- OLD path (fallback, unchanged) ----------
    size_t lds_duo  = (size_t)CH_DUO  * sizeof(__half2)
                    + (size_t)(LUT_DUO  + 1) * sizeof(float2);  // 77832 B
    size_t lds_solo = (size_t)CH_SOLO * sizeof(__half2)
                    + (size_t)(LUT_SOLO + 1) * sizeof(float2);  // ~148 KB

    int nb_duo = probe_blocks((const void*)&pc_scatter_lut<CH_DUO, LUT_DUO, BLK1>,
                              BLK1, lds_duo);
    int nb_solo = probe_blocks((const void*)&pc_scatter_lut<CH_SOLO, LUT_SOLO, BLK1>,
                               BLK1, lds_solo);

    bool use_duo = (nb_duo >= 2);
    int  CH, nch, S, cap;
    size_t lds;
    if (use_duo) {
        CH  = CH_DUO;  lds = lds_duo;
        nch = (n_atoms + CH - 1) / CH;
        cap = 512;
    } else {
        CH  = CH_SOLO; lds = lds_solo;
        nch = (n_atoms + CH - 1) / CH;
        cap = 256;
    }
    S = (cap / nch) & ~7;
    if (S < 8) S = 8;

    size_t avail = (ws_size > qd_b) ? ws_size - qd_b : 0;
    int S_fit = (int)(avail / ((size_t)n_atoms * sizeof(__half2)));
    if (S_fit < S) S = S_fit & ~7;

    bool ok = (use_duo || nb_solo >= 1) && S >= 8 && n_atoms > 0;

    if (ok) {
        __half2* qd      = (__half2*)d_ws;
        __half2* partial = (__half2*)((char*)d_ws + qd_b);
        int      gps     = (n4 + S - 1) / S;

        pc_pack_qd_h<<<(n_atoms + 255) / 256, 256, 0, stream>>>(q, dip, qd,
                                                                n_atoms);
        if (use_duo)
            pc_scatter_lut<CH_DUO, LUT_DUO, BLK1>
                <<<S * nch, BLK1, lds, stream>>>(
                    dist, idx_i, idx_j, qd, partial, n_edges, n4, S, gps,
                    n_atoms, nch);
        else
            pc_scatter_lut<CH_SOLO, LUT_SOLO, BLK1>
                <<<S * nch, BLK1, lds, stream>>>(
                    dist, idx_i, idx_j, qd, partial, n_edges, n4, S, gps,
                    n_atoms, nch);
        pc_reduce_vw<<<(n_atoms + 63) / 64, 256, 0, stream>>>(
            partial, q, dip, out, n_atoms, S);
    } else {
        hipMemsetAsync(out, 0, (size_t)n_atoms * sizeof(float), stream);
        int grid = (n_edges + 255) / 256;
        pc_dipole_edges_atomic<<<grid, 256, 0, stream>>>(
            q, dip, dist, idx_i, idx_j, out, n_edges);
    }
}

// Round 2
// 162.236 us; speedup vs baseline: 1.0141x; 1.0141x over previous
//
#include <hip/hip_runtime.h>
#include <hip/hip_bf16.h>
#include <hip/hip_fp16.h>

// Problem constants (match reference)
#define CUTOFF_C    12.0f
#define CUTOFF_SR_C 2.0f
#define CUTOFF_SQ_C 144.0f
#define KEHALF_C    7.199822675975274f

#define BLK1   1024

// Old-path duo config: 2 blocks/CU. 17408*4 + 1025*8 = 77832 B <= 80 KB.
#define CH_DUO   17408
#define LUT_DUO  1024
// Old-path solo config: 1 block/CU.
#define CH_SOLO  33792
#define LUT_SOLO 2048

// vw-scatter: no LUT in LDS -> CH*4 = 80000 B <= 80 KB, nch=5 for 100K atoms.
#define CH_REC   20000

__device__ __forceinline__ float edge_energy(float d, float qi, float qj,
                                             float di, float dj) {
    float inv_d   = __frcp_rn(d);
    float dsh     = __fsqrt_rn(fmaf(d, d, 1.0f));
    float inv_dsh = __frcp_rn(dsh);
    float x  = d * (1.0f / CUTOFF_SR_C);
    float x3 = x * x * x;
    float sw = fmaf(x3, fmaf(x, fmaf(x, -6.0f, 15.0f), -10.0f), 1.0f);
    float sw_off = (d < CUTOFF_SR_C) ? sw : 0.0f;
    float Eoq = inv_d   + fmaf(d,   (1.0f / CUTOFF_SQ_C), -(2.0f / CUTOFF_C));
    float Esq = inv_dsh + fmaf(dsh, (1.0f / CUTOFF_SQ_C), -(2.0f / CUTOFF_C));
    float Eq  = (KEHALF_C * qi * qj) * fmaf(sw_off, Esq - Eoq, Eoq);
    float Eod = inv_d * inv_d * inv_d;
    float Esd = inv_dsh * inv_dsh * inv_dsh;
    float Ed  = (KEHALF_C * di * dj) * fmaf(sw_off, Esd - Eod, Eod);
    return Eq + Ed;
}

// Exact radial factors (KEHALF folded): v = qj*F, w = dj*G.  (old path / LUT init)
__device__ __forceinline__ float2 fg_exact(float d) {
    float inv_d   = 1.0f / d;
    float dsh     = sqrtf(fmaf(d, d, 1.0f));
    float inv_dsh = 1.0f / dsh;
    float x  = d * (1.0f / CUTOFF_SR_C);
    float x3 = x * x * x;
    float sw = fmaf(x3, fmaf(x, fmaf(x, -6.0f, 15.0f), -10.0f), 1.0f);
    float sw_off = (d < CUTOFF_SR_C) ? sw : 0.0f;
    float Foq = inv_d   + fmaf(d,   (1.0f / CUTOFF_SQ_C), -(2.0f / CUTOFF_C));
    float Fsq = inv_dsh + fmaf(dsh, (1.0f / CUTOFF_SQ_C), -(2.0f / CUTOFF_C));
    float F   = fmaf(sw_off, Fsq - Foq, Foq);
    float God = inv_d * inv_d * inv_d;
    float Gsd = inv_dsh * inv_dsh * inv_dsh;
    float G   = fmaf(sw_off, Gsd - God, God);
    return make_float2(KEHALF_C * F, KEHALF_C * G);
}

__device__ __forceinline__ __half2 vw_make_exact(float d, __half2 hqdj) {
    float2 qdj = __half22float2(hqdj);
    float2 fg  = fg_exact(d);
    return __floats2half2_rn(qdj.x * fg.x, qdj.y * fg.y);
}

__device__ __forceinline__ unsigned h2bits(__half2 h) {
    union { __half2 h; unsigned u; } c; c.h = h; return c.u;
}
__device__ __forceinline__ __half2 bits2h(unsigned u) {
    union { unsigned u; __half2 h; } c; c.u = u; return c.h;
}
// half2 atomic add: HW atomicAdd(__half2*) (ds_pk_add_f16) if available.
template <typename T>
__device__ __forceinline__ auto atom_add_h2(T* p, T v, int)
    -> decltype(atomicAdd(p, v), void()) {
    atomicAdd(p, v);
}
template <typename T>
__device__ __forceinline__ void atom_add_h2(T* p, T v, long) {
    unsigned* u = (unsigned*)p;
    unsigned old = *u, assumed;
    do {
        assumed = old;
        __half2 sum = __hadd2(bits2h(assumed), v);
        old = atomicCAS(u, assumed, h2bits(sum));
    } while (old != assumed);
}

// Fast-exact per-edge radial factors via HW rcp/rsq (errors << fp16 rounding).
// Returns half2{qj*F, dipj*G} bit-pattern. Validity (d<=cutoff) selected by caller.
__device__ __forceinline__ unsigned vw_bits(float d, __half2 hq) {
    float inv_d   = __builtin_amdgcn_rcpf(d);
    float dsh2    = fmaf(d, d, 1.0f);
    float inv_dsh = __builtin_amdgcn_rsqf(dsh2);   // 1/sqrt(d^2+1)
    float dsh     = dsh2 * inv_dsh;                // sqrt(d^2+1)
    float x  = d * (1.0f / CUTOFF_SR_C);
    float x3 = x * x * x;
    float sw = fmaf(x3, fmaf(x, fmaf(x, -6.0f, 15.0f), -10.0f), 1.0f);
    float sw_off = (d < CUTOFF_SR_C) ? sw : 0.0f;
    float Foq = inv_d   + fmaf(d,   (1.0f / CUTOFF_SQ_C), -(2.0f / CUTOFF_C));
    float Fsq = inv_dsh + fmaf(dsh, (1.0f / CUTOFF_SQ_C), -(2.0f / CUTOFF_C));
    float F   = fmaf(sw_off, Fsq - Foq, Foq);
    float God = inv_d * inv_d * inv_d;
    float Gsd = inv_dsh * inv_dsh * inv_dsh;
    float G   = fmaf(sw_off, Gsd - God, God);
    float2 q2 = __half22float2(hq);
    __half2 vw = __floats2half2_rn((KEHALF_C * q2.x) * F, (KEHALF_C * q2.y) * G);
    return h2bits(vw);
}

// Pack {q, dip} -> half2 (4 B / atom), j-side gather table.
__global__ __launch_bounds__(256) void pc_pack_qd_h(
    const float* __restrict__ q,
    const float* __restrict__ dip,
    __half2*     __restrict__ qd,
    int n_atoms)
{
    int a = blockIdx.x * 256 + threadIdx.x;
    if (a < n_atoms) qd[a] = __floats2half2_rn(q[a], dip[a]);
}

// ---------------- PASS A: per-edge vw precompute (latency-batched) ----------
// Emits ONLY vw = half2{qj*F, dipj*G} per edge (4 B); idx_i is NOT copied —
// pass B reads the original input. Out-of-cutoff edges -> vw = 0 (exact).
// Each thread owns exactly TWO 4-edge groups (g, g+half): all 4 stream loads
// issued up-front (j first so the 8 gathers only wait on j), then 8 gathers,
// then compute + 2 dense uint4 stores. Two stall points per thread, no loop.
__global__ __launch_bounds__(256) void pc_edge_vw(
    const float*   __restrict__ dist,
    const int*     __restrict__ idx_j,
    const __half2* __restrict__ qd,
    uint4*         __restrict__ vwo,     // [n4] groups of 4 edges
    unsigned*      __restrict__ vws,     // scalar view (tail records)
    int n_edges, int n4, int half)
{
    const int t = blockIdx.x * 256 + (int)threadIdx.x;
    const int4*   j4p = (const int4*)idx_j;
    const float4* d4p = (const float4*)dist;

    if (t < half) {
        const int  ga = t;
        const int  gb = t + half;
        const bool vb = gb < n4;
        const int  gbs = vb ? gb : ga;    // safe addr, cndmask not branch

        // j-loads first, then d-loads: gathers wait only on the j pair.
        int4   ja = j4p[ga];
        int4   jb = j4p[gbs];
        float4 da = d4p[ga];
        float4 db = d4p[gbs];

        __half2 q0 = qd[ja.x], q1 = qd[ja.y], q2 = qd[ja.z], q3 = qd[ja.w];
        __half2 q4 = qd[jb.x], q5 = qd[jb.y], q6 = qd[jb.z], q7 = qd[jb.w];

        unsigned w0 = vw_bits(da.x, q0);
        unsigned w1 = vw_bits(da.y, q1);
        unsigned w2 = vw_bits(da.z, q2);
        unsigned w3 = vw_bits(da.w, q3);
        unsigned w4 = vw_bits(db.x, q4);
        unsigned w5 = vw_bits(db.y, q5);
        unsigned w6 = vw_bits(db.z, q6);
        unsigned w7 = vw_bits(db.w, q7);

        w0 = (da.x <= CUTOFF_C) ? w0 : 0u;
        w1 = (da.y <= CUTOFF_C) ? w1 : 0u;
        w2 = (da.z <= CUTOFF_C) ? w2 : 0u;
        w3 = (da.w <= CUTOFF_C) ? w3 : 0u;
        w4 = (db.x <= CUTOFF_C) ? w4 : 0u;
        w5 = (db.y <= CUTOFF_C) ? w5 : 0u;
        w6 = (db.z <= CUTOFF_C) ? w6 : 0u;
        w7 = (db.w <= CUTOFF_C) ? w7 : 0u;

        vwo[ga] = make_uint4(w0, w1, w2, w3);
        if (vb) vwo[gb] = make_uint4(w4, w5, w6, w7);
    }

    // scalar tail (n_edges % 4), handled by first threads of block 0
    const int tl = n_edges & 3;
    if (blockIdx.x == 0 && (int)threadIdx.x < tl) {
        int e = (n4 << 2) + (int)threadIdx.x;
        float d = dist[e];
        unsigned w = vw_bits(d, qd[idx_j[e]]);
        vws[e] = (d <= CUTOFF_C) ? w : 0u;
    }
}

// ---------------- PASS B: vw scatter ----------------
// Chunked-LDS scatter over precomputed vw: per edge just
// {lc = idx_i[e] - base; if (lc < CH) ds_pk_add_f16}. No gathers, no fg math.
// Block b: s = b % S (edge slice), c = b / S (atom chunk). S % 8 == 0 keeps
// same-slice blocks on one XCD so the nch chunk re-reads hit L2.
template <int CH, int BLK>
__global__ __launch_bounds__(BLK) void pc_scatter_vw(
    const int*      __restrict__ idx_i,
    const unsigned* __restrict__ vw,
    __half2*        __restrict__ partial,   // [S][n_atoms] half2 {sumv,sumw}
    int n_edges, int n4, int S, int gps, int n_atoms)
{
    extern __shared__ char smem[];
    __half2* acc2 = (__half2*)smem;                                  // CH

    const int s = blockIdx.x % S;
    const int c = blockIdx.x / S;
    const unsigned base = (unsigned)(c * CH);
    const int lim = min(CH, n_atoms - (int)base);

    const __half2 hzero = __floats2half2_rn(0.0f, 0.0f);
    for (int i = threadIdx.x; i < CH; i += BLK) acc2[i] = hzero;
    __syncthreads();

    const int4*  i4p = (const int4*)idx_i;
    const uint4* v4p = (const uint4*)vw;
    const int g0 = s * gps;
    const int g1 = min(g0 + gps, n4);
    for (int g = g0 + (int)threadIdx.x; g < g1; g += BLK) {
        int4  i4 = i4p[g];
        uint4 v4 = v4p[g];
        unsigned lc0 = (unsigned)i4.x - base;
        unsigned lc1 = (unsigned)i4.y - base;
        unsigned lc2 = (unsigned)i4.z - base;
        unsigned lc3 = (unsigned)i4.w - base;
        if (lc0 < (unsigned)CH) atom_add_h2(&acc2[lc0], bits2h(v4.x), 0);
        if (lc1 < (unsigned)CH) atom_add_h2(&acc2[lc1], bits2h(v4.y), 0);
        if (lc2 < (unsigned)CH) atom_add_h2(&acc2[lc2], bits2h(v4.z), 0);
        if (lc3 < (unsigned)CH) atom_add_h2(&acc2[lc3], bits2h(v4.w), 0);
    }

    if (s == S - 1) {  // scalar tail (n_edges % 4)
        for (int e = (n4 << 2) + (int)threadIdx.x; e < n_edges; e += BLK) {
            unsigned lc = (unsigned)idx_i[e] - base;
            if (lc < (unsigned)CH) atom_add_h2(&acc2[lc], bits2h(vw[e]), 0);
        }
    }

    __syncthreads();
    __half2* row = partial + (size_t)s * n_atoms + (int)base;
    for (int i = threadIdx.x; i < lim; i += BLK) row[i] = acc2[i];
}

// ---------------- OLD PATH (fallback): fused compute+scatter with LDS LUT ----
template <int CH, int LUTN, int BLK>
__global__ __launch_bounds__(BLK) void pc_scatter_lut(
    const float*   __restrict__ dist,
    const int*     __restrict__ idx_i,
    const int*     __restrict__ idx_j,
    const __half2* __restrict__ qd,
    __half2*       __restrict__ partial,   // [S][n_atoms] half2 {sumv,sumw}
    int n_edges, int n4, int S, int gps, int n_atoms, int nch)
{
    extern __shared__ char smem[];
    __half2* acc2 = (__half2*)smem;                                  // CH
    float2*  lut  = (float2*)(smem + (size_t)CH * sizeof(__half2));  // LUTN+1

    const int s    = blockIdx.x % S;
    const int c    = blockIdx.x / S;
    const int base = c * CH;
    const int lim  = min(CH, n_atoms - base);

    const __half2 hzero = __floats2half2_rn(0.0f, 0.0f);
    for (int i = threadIdx.x; i < CH; i += BLK) acc2[i] = hzero;

    const float hstep = CUTOFF_C / (float)LUTN;
    for (int k = threadIdx.x; k <= LUTN; k += BLK) {
        float d = fmaxf((float)k * hstep, 0.25f * hstep);
        lut[k] = fg_exact(d);
    }
    __syncthreads();

    const int g0 = s * gps;
    const int g1 = min(g0 + gps, n4);
    const int4*   idxi4 = (const int4*)idx_i;
    const int4*   idxj4 = (const int4*)idx_j;
    const float4* dist4 = (const float4*)dist;
    const float   dscale = (float)LUTN / CUTOFF_C;

    for (int g = g0 + (int)threadIdx.x; g < g1; g += BLK) {
        int4   i4 = idxi4[g];
        int4   j4 = idxj4[g];
        float4 d4 = dist4[g];

        int      ii[4] = { i4.x, i4.y, i4.z, i4.w };
        int      jj[4] = { j4.x, j4.y, j4.z, j4.w };
        float    dd[4] = { d4.x, d4.y, d4.z, d4.w };
        unsigned lc[4];
        bool     vl[4];
        __half2  qh[4];

        #pragma unroll
        for (int k = 0; k < 4; ++k) {
            lc[k] = (unsigned)(ii[k] - base);
            vl[k] = (lc[k] < (unsigned)CH) && (dd[k] <= CUTOFF_C);
        }
        #pragma unroll
        for (int k = 0; k < 4; ++k)
            qh[k] = vl[k] ? qd[jj[k]] : hzero;

        #pragma unroll
        for (int k = 0; k < 4; ++k) {
            if (vl[k]) {
                float t  = dd[k] * dscale;
                int   kk = min((int)t, LUTN - 1);
                float fr = t - (float)kk;
                float2 l0 = lut[kk];
                float2 l1 = lut[kk + 1];
                float F = fmaf(fr, l1.x - l0.x, l0.x);
                float G = fmaf(fr, l1.y - l0.y, l0.y);
                float2 qdj = __half22float2(qh[k]);
                __half2 vw = __floats2half2_rn(qdj.x * F, qdj.y * G);
                atom_add_h2(&acc2[lc[k]], vw, 0);
            }
        }
    }

    if (s == S - 1) {  // scalar tail (n_edges % 4)
        for (int e = (n4 << 2) + (int)threadIdx.x; e < n_edges; e += BLK) {
            int i = idx_i[e];
            float d = dist[e];
            unsigned local = (unsigned)(i - base);
            if (local < (unsigned)CH && d <= CUTOFF_C) {
                __half2 vw = vw_make_exact(d, qd[idx_j[e]]);
                atom_add_h2(&acc2[local], vw, 0);
            }
        }
    }

    __syncthreads();
    __half2* row = partial + (size_t)s * n_atoms + base;
    for (int i = threadIdx.x; i < lim; i += BLK) row[i] = acc2[i];
}

// out[a] = q[a]*sum_s(v) + dip[a]*sum_s(w) — exact fp32 recombination.
__global__ __launch_bounds__(256) void pc_reduce_vw(
    const __half2* __restrict__ partial,   // [S][n_atoms]
    const float*   __restrict__ q,
    const float*   __restrict__ dip,
    float*         __restrict__ out,
    int n_atoms, int S)
{
    __shared__ float2 sh[256];
    int a0   = blockIdx.x * 64;
    int lane = threadIdx.x & 63;
    int w    = threadIdx.x >> 6;
    int a    = a0 + lane;

    float sv = 0.0f, sw = 0.0f;
    if (a < n_atoms) {
        int per = S >> 2;                  // S % 4 == 0
        const __half2* p = partial + a;
        int s = w * per, send = s + per;
        for (; s < send; ++s) {
            float2 t = __half22float2(p[(size_t)s * n_atoms]);
            sv += t.x; sw += t.y;
        }
    }
    sh[threadIdx.x] = make_float2(sv, sw);
    __syncthreads();
    if (w == 0 && a < n_atoms) {
        float2 t0 = sh[lane],       t1 = sh[64 + lane];
        float2 t2 = sh[128 + lane], t3 = sh[192 + lane];
        float fv = (t0.x + t1.x) + (t2.x + t3.x);
        float fw = (t0.y + t1.y) + (t2.y + t3.y);
        out[a] = fmaf(q[a], fv, dip[a] * fw);
    }
}

// Full-precision global-atomic fallback (probe failure / tiny ws).
__global__ __launch_bounds__(256) void pc_dipole_edges_atomic(
    const float* __restrict__ q,
    const float* __restrict__ dip,
    const float* __restrict__ dist,
    const int*   __restrict__ idx_i,
    const int*   __restrict__ idx_j,
    float*       __restrict__ out,
    int n_edges)
{
    int t = blockIdx.x * blockDim.x + threadIdx.x;
    const int stride = gridDim.x * blockDim.x;
    for (int e = t; e < n_edges; e += stride) {
        float d = dist[e];
        if (d > CUTOFF_C) continue;
        int i = idx_i[e], j = idx_j[e];
        atomicAdd(&out[i], edge_energy(d, q[i], q[j], dip[i], dip[j]));
    }
}

static int probe_blocks(const void* f, int blk, size_t lds) {
    hipError_t e1 = hipFuncSetAttribute(
        f, hipFuncAttributeMaxDynamicSharedMemorySize, (int)lds);
    int nb = 0;
    hipError_t e2 = hipOccupancyMaxActiveBlocksPerMultiprocessor(&nb, f, blk, lds);
    if (e1 != hipSuccess || e2 != hipSuccess) return 0;
    return nb;
}

extern "C" void kernel_launch(void* const* d_in, const int* in_sizes, int n_in,
                              void* d_out, int out_size, void* d_ws, size_t ws_size,
                              hipStream_t stream) {
    const float* q     = (const float*)d_in[0];
    const float* dip   = (const float*)d_in[1];
    const float* dist  = (const float*)d_in[2];
    const int*   idx_i = (const int*)d_in[3];
    const int*   idx_j = (const int*)d_in[4];
    float*       out   = (float*)d_out;

    int n_edges = in_sizes[2];
    int n_atoms = out_size;
    int n4      = n_edges >> 2;

    // ---------- NEW path: vw precompute + vw scatter ----------
    size_t qd_b    = ((size_t)n_atoms * sizeof(__half2) + 255) & ~(size_t)255;
    size_t vw_b    = (((size_t)n_edges * 4) + 255) & ~(size_t)255;
    size_t lds_rec = (size_t)CH_REC * sizeof(__half2);               // 80000 B

    int nb_rec = probe_blocks((const void*)&pc_scatter_vw<CH_REC, BLK1>,
                              BLK1, lds_rec);

    int S_new = 0, nch_new = 0;
    if (nb_rec >= 2 && n_atoms > 0 && n4 > 0 && ws_size > qd_b + vw_b) {
        nch_new = (n_atoms + CH_REC - 1) / CH_REC;                   // 5 for 100K
        int cap = 512;                                               // 2/CU * 256
        S_new = (cap / nch_new) & ~7;                                // 96
        size_t avail = ws_size - qd_b - vw_b;
        int S_fit = (int)(avail / ((size_t)n_atoms * sizeof(__half2))) & ~7;
        if (S_fit < S_new) S_new = S_fit;
    }

    if (S_new >= 8) {
        __half2*  qd      = (__half2*)d_ws;
        unsigned* vw      = (unsigned*)((char*)d_ws + qd_b);
        __half2*  partial = (__half2*)((char*)d_ws + qd_b + vw_b);
        int       gps     = (n4 + S_new - 1) / S_new;
        int       half    = (n4 + 1) >> 1;
        int       gridA   = (half + 255) / 256;
        if (gridA < 1) gridA = 1;

        pc_pack_qd_h<<<(n_atoms + 255) / 256, 256, 0, stream>>>(q, dip, qd,
                                                                n_atoms);
        pc_edge_vw<<<gridA, 256, 0, stream>>>(dist, idx_j, qd,
                                              (uint4*)vw, vw,
                                              n_edges, n4, half);
        pc_scatter_vw<CH_REC, BLK1>
            <<<S_new * nch_new, BLK1, lds_rec, stream>>>(
                idx_i, vw, partial, n_edges, n4, S_new, gps, n_atoms);
        pc_reduce_vw<<<(n_atoms + 63) / 64, 256, 0, stream>>>(
            partial, q, dip, out, n_atoms, S_new);
        return;
    }

    // ---------- OLD path (fallback, unchanged) ----------
    size_t lds_duo  = (size_t)CH_DUO  * sizeof(__half2)
                    + (size_t)(LUT_DUO  + 1) * sizeof(float2);  // 77832 B
    size_t lds_solo = (size_t)CH_SOLO * sizeof(__half2)
                    + (size_t)(LUT_SOLO + 1) * sizeof(float2);  // ~148 KB

    int nb_duo = probe_blocks((const void*)&pc_scatter_lut<CH_DUO, LUT_DUO, BLK1>,
                              BLK1, lds_duo);
    int nb_solo = probe_blocks((const void*)&pc_scatter_lut<CH_SOLO, LUT_SOLO, BLK1>,
                               BLK1, lds_solo);

    bool use_duo = (nb_duo >= 2);
    int  CH, nch, S, cap;
    size_t lds;
    if (use_duo) {
        CH  = CH_DUO;  lds = lds_duo;
        nch = (n_atoms + CH - 1) / CH;
        cap = 512;
    } else {
        CH  = CH_SOLO; lds = lds_solo;
        nch = (n_atoms + CH - 1) / CH;
        cap = 256;
    }
    S = (cap / nch) & ~7;
    if (S < 8) S = 8;

    size_t avail = (ws_size > qd_b) ? ws_size - qd_b : 0;
    int S_fit = (int)(avail / ((size_t)n_atoms * sizeof(__half2)));
    if (S_fit < S) S = S_fit & ~7;

    bool ok = (use_duo || nb_solo >= 1) && S >= 8 && n_atoms > 0;

    if (ok) {
        __half2* qd      = (__half2*)d_ws;
        __half2* partial = (__half2*)((char*)d_ws + qd_b);
        int      gps     = (n4 + S - 1) / S;

        pc_pack_qd_h<<<(n_atoms + 255) / 256, 256, 0, stream>>>(q, dip, qd,
                                                                n_atoms);
        if (use_duo)
            pc_scatter_lut<CH_DUO, LUT_DUO, BLK1>
                <<<S * nch, BLK1, lds, stream>>>(
                    dist, idx_i, idx_j, qd, partial, n_edges, n4, S, gps,
                    n_atoms, nch);
        else
            pc_scatter_lut<CH_SOLO, LUT_SOLO, BLK1>
                <<<S * nch, BLK1, lds, stream>>>(
                    dist, idx_i, idx_j, qd, partial, n_edges, n4, S, gps,
                    n_atoms, nch);
        pc_reduce_vw<<<(n_atoms + 63) / 64, 256, 0, stream>>>(
            partial, q, dip, out, n_atoms, S);
    } else {
        hipMemsetAsync(out, 0, (size_t)n_atoms * sizeof(float), stream);
        int grid = (n_edges + 255) / 256;
        pc_dipole_edges_atomic<<<grid, 256, 0, stream>>>(
            q, dip, dist, idx_i, idx_j, out, n_edges);
    }
}